// Round 1
// baseline (225.719 us; speedup 1.0000x reference)
//
#include <hip/hip_runtime.h>
#include <math.h>

#define TT 2048
#define HH 128

// ---------------- generic dense: out[t][h] = b[h] + dot(x[t], w[h]) ----------------
// 16 rows per block, 256 threads: h = tid&127, ry = tid>>7 handles 8 rows each.
template<int C, int ACT>
__global__ void dense_kernel(const float* __restrict__ x, const float* __restrict__ w,
                             const float* __restrict__ b, float* __restrict__ out) {
    __shared__ float xs[16 * C];
    int t0 = blockIdx.x * 16;
    int tid = threadIdx.x;
    for (int idx = tid; idx < 16 * C; idx += 256) xs[idx] = x[t0 * C + idx];
    __syncthreads();
    int h = tid & 127;
    int ry = tid >> 7;
    float acc[8];
#pragma unroll
    for (int r = 0; r < 8; r++) acc[r] = 0.f;
    const float* wr = w + h * C;
    for (int c = 0; c < C; c++) {
        float wv = wr[c];
#pragma unroll
        for (int r = 0; r < 8; r++) acc[r] += xs[(ry * 8 + r) * C + c] * wv;
    }
    float bh = b[h];
#pragma unroll
    for (int r = 0; r < 8; r++) {
        float v = acc[r] + bh;
        if (ACT == 1) v = v > 0.f ? v : 0.01f * v;
        out[(t0 + ry * 8 + r) * HH + h] = v;
    }
}

// ---------------- fused projections: v, q, k, o_sig, logsig(f), exp(i) ----------------
__global__ void proj_kernel(const float* __restrict__ x,
                            const float* __restrict__ w_v, const float* __restrict__ b_v,
                            const float* __restrict__ w_q, const float* __restrict__ b_q,
                            const float* __restrict__ w_k, const float* __restrict__ b_k,
                            const float* __restrict__ w_o, const float* __restrict__ b_o,
                            const float* __restrict__ w_f, const float* __restrict__ b_f,
                            const float* __restrict__ w_i, const float* __restrict__ b_i,
                            float* __restrict__ vout, float* __restrict__ qout,
                            float* __restrict__ kout, float* __restrict__ oout,
                            float* __restrict__ logsig, float* __restrict__ iexp) {
    __shared__ float xs[16 * HH];
    __shared__ float redf[256];
    __shared__ float redi[256];
    int t0 = blockIdx.x * 16;
    int tid = threadIdx.x;
    for (int idx = tid; idx < 16 * HH; idx += 256) xs[idx] = x[t0 * HH + idx];
    __syncthreads();
    int h = tid & 127;
    int ry = tid >> 7;
    float av[8], aq[8], ak[8], ao[8];
#pragma unroll
    for (int r = 0; r < 8; r++) { av[r] = 0.f; aq[r] = 0.f; ak[r] = 0.f; ao[r] = 0.f; }
    const float* wvr = w_v + h * HH;
    const float* wqr = w_q + h * HH;
    const float* wkr = w_k + h * HH;
    const float* wor = w_o + h * HH;
    for (int c = 0; c < HH; c++) {
        float wv = wvr[c], wq = wqr[c], wk = wkr[c], wo = wor[c];
#pragma unroll
        for (int r = 0; r < 8; r++) {
            float xv = xs[(ry * 8 + r) * HH + c];
            av[r] += xv * wv;
            aq[r] += xv * wq;
            ak[r] += xv * wk;
            ao[r] += xv * wo;
        }
    }
    const float kscale = 0.088388347648318447f; // 1/sqrt(128)
    float bv = b_v[h], bq = b_q[h], bk = b_k[h], bo = b_o[h];
#pragma unroll
    for (int r = 0; r < 8; r++) {
        int t = t0 + ry * 8 + r;
        vout[t * HH + h] = av[r] + bv;
        qout[t * HH + h] = aq[r] + bq;
        kout[t * HH + h] = ak[r] * kscale + bk;
        float opre = ao[r] + bo;
        oout[t * HH + h] = 1.0f / (1.0f + expf(-opre));
    }
    // f and i projections ([1,H] weights): thread = (row r16, chunk seg of 8 cols)
    int r16 = tid >> 4;
    int seg = tid & 15;
    float pf = 0.f, pi = 0.f;
#pragma unroll
    for (int j = 0; j < 8; j++) {
        float xv = xs[r16 * HH + seg * 8 + j];
        pf += xv * w_f[seg * 8 + j];
        pi += xv * w_i[seg * 8 + j];
    }
    redf[r16 * 16 + seg] = pf;
    redi[r16 * 16 + seg] = pi;
    __syncthreads();
    if (tid < 16) {
        float sf = 0.f, si = 0.f;
        for (int j = 0; j < 16; j++) { sf += redf[tid * 16 + j]; si += redi[tid * 16 + j]; }
        float f_raw = sf + b_f[0];
        float i_raw = si + b_i[0];
        // stable log(sigmoid(f))
        float ls = (f_raw < 0.f) ? (f_raw - log1pf(expf(f_raw))) : (-log1pf(expf(-f_raw)));
        logsig[t0 + tid] = ls;
        iexp[t0 + tid] = expf(i_raw);
    }
}

// ---------------- segmented scan: As (seg-local cumsum of logsig), lr (last reset) ----
__global__ void scan_kernel(const float* __restrict__ logsig, const int* __restrict__ start,
                            float* __restrict__ As, int* __restrict__ lr) {
    __shared__ float ssum[256];
    __shared__ int sflag[256];
    __shared__ int sidx[256];
    __shared__ float pre_sum[256];
    __shared__ int pre_idx[256];
    int tid = threadIdx.x;
    int base = tid * 8;
    // local composed map over 8 consecutive elements
    float s = 0.f; int flag = 0; int idx = 0;
    for (int j = 0; j < 8; j++) {
        int t = base + j;
        int f = start[t];
        float val = logsig[t];
        if (f) { s = val; flag = 1; idx = t; }
        else   { s = s + val; }
    }
    ssum[tid] = s; sflag[tid] = flag; sidx[tid] = idx;
    __syncthreads();
    if (tid == 0) {
        float ps = 0.f; int pidx = 0;
        for (int i = 0; i < 256; i++) {
            pre_sum[i] = ps; pre_idx[i] = pidx;
            if (sflag[i]) { ps = ssum[i]; pidx = sidx[i]; }
            else          { ps = ps + ssum[i]; }
        }
    }
    __syncthreads();
    float p = pre_sum[tid]; int pidx = pre_idx[tid];
    for (int j = 0; j < 8; j++) {
        int t = base + j;
        int f = start[t];
        float val = logsig[t];
        if (f) { p = val; pidx = t; }
        else   { p = p + val; }
        As[t] = p; lr[t] = pidx;
    }
}

// ---------------- attention over [lastreset(t), t] ----------------
__global__ void attn_kernel(const float* __restrict__ v, const float* __restrict__ k,
                            const float* __restrict__ q, const float* __restrict__ osig,
                            const float* __restrict__ iexp, const float* __restrict__ As,
                            const int* __restrict__ lr, float* __restrict__ hout) {
    int t = blockIdx.x;
    int lane = threadIdx.x; // 64
    float q0 = q[t * HH + lane];
    float q1 = q[t * HH + lane + 64];
    float At = As[t];
    int tstart = lr[t];
    float num0 = 0.f, num1 = 0.f, dsum = 0.f;
    for (int tp = tstart; tp <= t; tp++) {
        float p = k[tp * HH + lane] * q0 + k[tp * HH + lane + 64] * q1;
#pragma unroll
        for (int off = 32; off >= 1; off >>= 1) p += __shfl_xor(p, off, 64);
        float coeff = expf(At - As[tp]) * iexp[tp] * p;
        num0 += coeff * v[tp * HH + lane];
        num1 += coeff * v[tp * HH + lane + 64];
        dsum += coeff;
    }
    float den = fmaxf(fabsf(dsum), 1.0f);
    hout[t * HH + lane]      = osig[t * HH + lane]      * num0 / den;
    hout[t * HH + lane + 64] = osig[t * HH + lane + 64] * num1 / den;
}

// ---------------- ff: z = lrelu(concat([h, e]) @ w_ff.T + b_ff) ----------------
__global__ void ff_kernel(const float* __restrict__ hbuf, const float* __restrict__ e,
                          const float* __restrict__ w, const float* __restrict__ b,
                          float* __restrict__ z) {
    __shared__ float xs[16 * 256];
    int t0 = blockIdx.x * 16;
    int tid = threadIdx.x;
    for (int idx = tid; idx < 16 * HH; idx += 256) {
        int r = idx >> 7, c = idx & 127;
        xs[r * 256 + c]       = hbuf[(t0 + r) * HH + c];
        xs[r * 256 + 128 + c] = e[(t0 + r) * HH + c];
    }
    __syncthreads();
    int h = tid & 127;
    int ry = tid >> 7;
    float acc[8];
#pragma unroll
    for (int r = 0; r < 8; r++) acc[r] = 0.f;
    const float* wr = w + h * 256;
    for (int c = 0; c < 256; c++) {
        float wv = wr[c];
#pragma unroll
        for (int r = 0; r < 8; r++) acc[r] += xs[(ry * 8 + r) * 256 + c] * wv;
    }
    float bh = b[h];
#pragma unroll
    for (int r = 0; r < 8; r++) {
        float vv = acc[r] + bh;
        z[(t0 + ry * 8 + r) * HH + h] = vv > 0.f ? vv : 0.01f * vv;
    }
}

extern "C" void kernel_launch(void* const* d_in, const int* in_sizes, int n_in,
                              void* d_out, int out_size, void* d_ws, size_t ws_size,
                              hipStream_t stream) {
    const float* emb   = (const float*)d_in[0];
    const int*   start = (const int*)  d_in[1];
    const float* w_in  = (const float*)d_in[2];
    const float* b_in  = (const float*)d_in[3];
    const float* w_out = (const float*)d_in[4];
    const float* b_out = (const float*)d_in[5];
    const float* w_f   = (const float*)d_in[6];
    const float* b_f   = (const float*)d_in[7];
    const float* w_i   = (const float*)d_in[8];
    const float* b_i   = (const float*)d_in[9];
    const float* w_v   = (const float*)d_in[10];
    const float* b_v   = (const float*)d_in[11];
    const float* w_q   = (const float*)d_in[12];
    const float* b_q   = (const float*)d_in[13];
    const float* w_k   = (const float*)d_in[14];
    const float* b_k   = (const float*)d_in[15];
    const float* w_o   = (const float*)d_in[16];
    const float* b_o   = (const float*)d_in[17];
    const float* w_ff  = (const float*)d_in[18];
    const float* b_ff  = (const float*)d_in[19];
    float* out = (float*)d_out;

    float* ws = (float*)d_ws;
    float* e      = ws; ws += TT * HH;
    float* z      = ws; ws += TT * HH;
    float* vbuf   = ws; ws += TT * HH;
    float* kbuf   = ws; ws += TT * HH;
    float* qbuf   = ws; ws += TT * HH;
    float* obuf   = ws; ws += TT * HH;
    float* hbuf   = ws; ws += TT * HH;
    float* iexp   = ws; ws += TT;
    float* logsig = ws; ws += TT;
    float* As     = ws; ws += TT;
    int*   lr     = (int*)ws;

    dense_kernel<128, 0><<<TT / 16, 256, 0, stream>>>(emb, w_in, b_in, e);

    const float* x = e;
    for (int l = 0; l < 2; l++) {
        proj_kernel<<<TT / 16, 256, 0, stream>>>(
            x,
            w_v + l * HH * HH, b_v + l * HH,
            w_q + l * HH * HH, b_q + l * HH,
            w_k + l * HH * HH, b_k + l * HH,
            w_o + l * HH * HH, b_o + l * HH,
            w_f + l * HH, b_f + l,
            w_i + l * HH, b_i + l,
            vbuf, qbuf, kbuf, obuf, logsig, iexp);
        scan_kernel<<<1, 256, 0, stream>>>(logsig, start, As, lr);
        attn_kernel<<<TT, 64, 0, stream>>>(vbuf, kbuf, qbuf, obuf, iexp, As, lr, hbuf);
        ff_kernel<<<TT / 16, 256, 0, stream>>>(hbuf, e, w_ff + l * HH * 2 * HH, b_ff + l * HH, z);
        x = z;
    }
    dense_kernel<128, 0><<<TT / 16, 256, 0, stream>>>(z, w_out, b_out, out);
}

// Round 2
// 173.557 us; speedup vs baseline: 1.3005x; 1.3005x over previous
//
#include <hip/hip_runtime.h>
#include <math.h>

#define TT 2048
#define HH 128
#define ROWS 8
#define SP 132  // LDS row stride in floats (pad 128+4 to break bank aliasing)

__device__ __forceinline__ float dot4(float4 a, float4 b) {
    return a.x * b.x + a.y * b.y + a.z * b.z + a.w * b.w;
}

// Accumulate 4 outputs (rows h0..h0+3 of w, row-major stride S) over 128 columns of x.
template<int S>
__device__ __forceinline__ void gemv4_acc(const float* __restrict__ w,
                                          const float* __restrict__ x, float4* acc) {
#pragma unroll 8
    for (int c = 0; c < 128; c += 4) {
        float4 x4 = *(const float4*)(x + c);
        float4 w0 = *(const float4*)(w + c);
        float4 w1 = *(const float4*)(w + S + c);
        float4 w2 = *(const float4*)(w + 2 * S + c);
        float4 w3 = *(const float4*)(w + 3 * S + c);
        acc->x += dot4(x4, w0);
        acc->y += dot4(x4, w1);
        acc->z += dot4(x4, w2);
        acc->w += dot4(x4, w3);
    }
}

// Stage 8 rows x 128 cols from global (row stride HH) into LDS (row stride SP).
__device__ __forceinline__ void stage_rows(const float* __restrict__ src, int t0,
                                           float* __restrict__ dst) {
    int idx = threadIdx.x * 4;
    int r = idx >> 7, c = idx & 127;
    *(float4*)(dst + r * SP + c) = *(const float4*)(src + t0 * HH + idx);
}

// v,q,k,o projections for one row, 4 h-outputs per thread. xrow points at LDS row.
__device__ __forceinline__ void proj_vqko(int t, int h0, const float* __restrict__ xrow,
        const float* __restrict__ w_v, const float* __restrict__ b_v,
        const float* __restrict__ w_q, const float* __restrict__ b_q,
        const float* __restrict__ w_k, const float* __restrict__ b_k,
        const float* __restrict__ w_o, const float* __restrict__ b_o,
        float* __restrict__ vb, float* __restrict__ qb,
        float* __restrict__ kb, float* __restrict__ ob) {
    float4 av = {0, 0, 0, 0}, aq = {0, 0, 0, 0}, ak = {0, 0, 0, 0}, ao = {0, 0, 0, 0};
    gemv4_acc<128>(w_v + h0 * 128, xrow, &av);
    gemv4_acc<128>(w_q + h0 * 128, xrow, &aq);
    gemv4_acc<128>(w_k + h0 * 128, xrow, &ak);
    gemv4_acc<128>(w_o + h0 * 128, xrow, &ao);
    const float ks = 0.088388347648318447f;  // 1/sqrt(128), applied pre-bias
    float4 bv = *(const float4*)(b_v + h0);
    float4 bq = *(const float4*)(b_q + h0);
    float4 bk = *(const float4*)(b_k + h0);
    float4 bo = *(const float4*)(b_o + h0);
    float4 ov, oq, okk, oo;
    ov.x = av.x + bv.x; ov.y = av.y + bv.y; ov.z = av.z + bv.z; ov.w = av.w + bv.w;
    oq.x = aq.x + bq.x; oq.y = aq.y + bq.y; oq.z = aq.z + bq.z; oq.w = aq.w + bq.w;
    okk.x = ak.x * ks + bk.x; okk.y = ak.y * ks + bk.y;
    okk.z = ak.z * ks + bk.z; okk.w = ak.w * ks + bk.w;
    oo.x = 1.f / (1.f + expf(-(ao.x + bo.x)));
    oo.y = 1.f / (1.f + expf(-(ao.y + bo.y)));
    oo.z = 1.f / (1.f + expf(-(ao.z + bo.z)));
    oo.w = 1.f / (1.f + expf(-(ao.w + bo.w)));
    *(float4*)(vb + t * HH + h0) = ov;
    *(float4*)(qb + t * HH + h0) = oq;
    *(float4*)(kb + t * HH + h0) = okk;
    *(float4*)(ob + t * HH + h0) = oo;
}

// f/i scalar projections for the block's 8 rows; wave 0 only (no sync after!).
__device__ __forceinline__ void proj_fi(int t0, const float* __restrict__ xls,
        const float* __restrict__ w_f, const float* __restrict__ b_f,
        const float* __restrict__ w_i, const float* __restrict__ b_i,
        const int* __restrict__ start, float* __restrict__ g, float* __restrict__ iexp) {
    int tid = threadIdx.x;
    if (tid < 64) {
        int row = tid >> 3, cc = tid & 7;
        const float* x = xls + row * SP + cc * 16;
        const float* wf = w_f + cc * 16;
        const float* wi = w_i + cc * 16;
        float pf = 0.f, pi = 0.f;
#pragma unroll
        for (int j = 0; j < 16; j++) {
            float xv = x[j];
            pf += xv * wf[j];
            pi += xv * wi[j];
        }
        pf += __shfl_xor(pf, 1, 64); pf += __shfl_xor(pf, 2, 64); pf += __shfl_xor(pf, 4, 64);
        pi += __shfl_xor(pi, 1, 64); pi += __shfl_xor(pi, 2, 64); pi += __shfl_xor(pi, 4, 64);
        if (cc == 0) {
            int t = t0 + row;
            float fr = pf + b_f[0];
            g[t] = start[t] ? 0.f : 1.f / (1.f + expf(-fr));
            iexp[t] = expf(pi + b_i[0]);
        }
    }
}

// mLSTM attention via backward walk within the episode segment.
// Half-wave (32 lanes) per row, 4 h per lane; writes h into LDS hs.
__device__ __forceinline__ void attn_rows(int t0,
        const float* __restrict__ kb, const float* __restrict__ vb,
        const float* __restrict__ qb, const float* __restrict__ ob,
        const float* __restrict__ g, const float* __restrict__ iexp,
        const int* __restrict__ start, float* __restrict__ hs) {
    int tid = threadIdx.x;
    int lane = tid & 63;
    int wv = tid >> 6;
    int sub = lane >> 5;
    int li = lane & 31;
    int r = wv * 2 + sub;
    int t = t0 + r;
    float4 q4 = *(const float4*)(qb + t * HH + 4 * li);
    float4 num = {0, 0, 0, 0};
    float dsum = 0.f;
    float decay = 1.f;
    int tp = t;
    while (true) {
        float4 k4 = *(const float4*)(kb + tp * HH + 4 * li);
        float p = dot4(k4, q4);
        p += __shfl_xor(p, 16, 64);
        p += __shfl_xor(p, 8, 64);
        p += __shfl_xor(p, 4, 64);
        p += __shfl_xor(p, 2, 64);
        p += __shfl_xor(p, 1, 64);
        float coeff = decay * iexp[tp] * p;
        float4 v4 = *(const float4*)(vb + tp * HH + 4 * li);
        num.x += coeff * v4.x; num.y += coeff * v4.y;
        num.z += coeff * v4.z; num.w += coeff * v4.w;
        dsum += coeff;
        if (tp == 0 || start[tp]) break;  // reset step included, then stop
        decay *= g[tp];
        tp--;
    }
    float inv = 1.f / fmaxf(fabsf(dsum), 1.f);
    float4 o4 = *(const float4*)(ob + t * HH + 4 * li);
    float4 h4;
    h4.x = o4.x * num.x * inv; h4.y = o4.y * num.y * inv;
    h4.z = o4.z * num.z * inv; h4.w = o4.w * num.w * inv;
    *(float4*)(hs + r * SP + 4 * li) = h4;
}

// ---------------- K1: e = emb @ w_in.T + b_in; layer-0 projections ----------------
__global__ __launch_bounds__(256) void k1_kernel(
        const float* __restrict__ emb, const int* __restrict__ start,
        const float* __restrict__ w_in, const float* __restrict__ b_in,
        const float* __restrict__ w_v, const float* __restrict__ b_v,
        const float* __restrict__ w_q, const float* __restrict__ b_q,
        const float* __restrict__ w_k, const float* __restrict__ b_k,
        const float* __restrict__ w_o, const float* __restrict__ b_o,
        const float* __restrict__ w_f, const float* __restrict__ b_f,
        const float* __restrict__ w_i, const float* __restrict__ b_i,
        float* __restrict__ e, float* __restrict__ kb, float* __restrict__ vb,
        float* __restrict__ qb, float* __restrict__ ob,
        float* __restrict__ g, float* __restrict__ iexp) {
    __shared__ float xs[ROWS * SP];
    __shared__ float es[ROWS * SP];
    int tid = threadIdx.x;
    int t0 = blockIdx.x * ROWS;
    stage_rows(emb, t0, xs);
    __syncthreads();
    int hg = tid >> 3, row = tid & 7, h0 = hg * 4;
    int t = t0 + row;
    float4 a = {0, 0, 0, 0};
    gemv4_acc<128>(w_in + h0 * 128, xs + row * SP, &a);
    float4 b4 = *(const float4*)(b_in + h0);
    a.x += b4.x; a.y += b4.y; a.z += b4.z; a.w += b4.w;
    *(float4*)(e + t * HH + h0) = a;
    *(float4*)(es + row * SP + h0) = a;
    __syncthreads();
    proj_vqko(t, h0, es + row * SP, w_v, b_v, w_q, b_q, w_k, b_k, w_o, b_o, vb, qb, kb, ob);
    proj_fi(t0, es, w_f, b_f, w_i, b_i, start, g, iexp);
}

// ---------------- K2: attn0 + ff0 + layer-1 projections ----------------
__global__ __launch_bounds__(256) void k2_kernel(
        const int* __restrict__ start, const float* __restrict__ e,
        const float* __restrict__ k0, const float* __restrict__ v0,
        const float* __restrict__ q0, const float* __restrict__ o0,
        const float* __restrict__ g0, const float* __restrict__ i0,
        const float* __restrict__ w_ff, const float* __restrict__ b_ff,
        const float* __restrict__ w_v, const float* __restrict__ b_v,
        const float* __restrict__ w_q, const float* __restrict__ b_q,
        const float* __restrict__ w_k, const float* __restrict__ b_k,
        const float* __restrict__ w_o, const float* __restrict__ b_o,
        const float* __restrict__ w_f, const float* __restrict__ b_f,
        const float* __restrict__ w_i, const float* __restrict__ b_i,
        float* __restrict__ kb, float* __restrict__ vb,
        float* __restrict__ qb, float* __restrict__ ob,
        float* __restrict__ g, float* __restrict__ iexp) {
    __shared__ float es[ROWS * SP];
    __shared__ float hs[ROWS * SP];
    __shared__ float zs[ROWS * SP];
    int tid = threadIdx.x;
    int t0 = blockIdx.x * ROWS;
    stage_rows(e, t0, es);
    attn_rows(t0, k0, v0, q0, o0, g0, i0, start, hs);
    __syncthreads();
    int hg = tid >> 3, row = tid & 7, h0 = hg * 4;
    int t = t0 + row;
    // ff: z = lrelu([h, e] @ w_ff.T + b_ff)
    float4 a = {0, 0, 0, 0};
    gemv4_acc<256>(w_ff + h0 * 256, hs + row * SP, &a);
    gemv4_acc<256>(w_ff + h0 * 256 + 128, es + row * SP, &a);
    float4 b4 = *(const float4*)(b_ff + h0);
    a.x += b4.x; a.y += b4.y; a.z += b4.z; a.w += b4.w;
    a.x = a.x > 0.f ? a.x : 0.01f * a.x;
    a.y = a.y > 0.f ? a.y : 0.01f * a.y;
    a.z = a.z > 0.f ? a.z : 0.01f * a.z;
    a.w = a.w > 0.f ? a.w : 0.01f * a.w;
    *(float4*)(zs + row * SP + h0) = a;
    __syncthreads();
    proj_vqko(t, h0, zs + row * SP, w_v, b_v, w_q, b_q, w_k, b_k, w_o, b_o, vb, qb, kb, ob);
    proj_fi(t0, zs, w_f, b_f, w_i, b_i, start, g, iexp);
}

// ---------------- K3: attn1 + ff1 + final dense ----------------
__global__ __launch_bounds__(256) void k3_kernel(
        const int* __restrict__ start, const float* __restrict__ e,
        const float* __restrict__ k1, const float* __restrict__ v1,
        const float* __restrict__ q1, const float* __restrict__ o1,
        const float* __restrict__ g1, const float* __restrict__ i1,
        const float* __restrict__ w_ff, const float* __restrict__ b_ff,
        const float* __restrict__ w_out, const float* __restrict__ b_out,
        float* __restrict__ out) {
    __shared__ float es[ROWS * SP];
    __shared__ float hs[ROWS * SP];
    __shared__ float zs[ROWS * SP];
    int tid = threadIdx.x;
    int t0 = blockIdx.x * ROWS;
    stage_rows(e, t0, es);
    attn_rows(t0, k1, v1, q1, o1, g1, i1, start, hs);
    __syncthreads();
    int hg = tid >> 3, row = tid & 7, h0 = hg * 4;
    int t = t0 + row;
    float4 a = {0, 0, 0, 0};
    gemv4_acc<256>(w_ff + h0 * 256, hs + row * SP, &a);
    gemv4_acc<256>(w_ff + h0 * 256 + 128, es + row * SP, &a);
    float4 b4 = *(const float4*)(b_ff + h0);
    a.x += b4.x; a.y += b4.y; a.z += b4.z; a.w += b4.w;
    a.x = a.x > 0.f ? a.x : 0.01f * a.x;
    a.y = a.y > 0.f ? a.y : 0.01f * a.y;
    a.z = a.z > 0.f ? a.z : 0.01f * a.z;
    a.w = a.w > 0.f ? a.w : 0.01f * a.w;
    *(float4*)(zs + row * SP + h0) = a;
    __syncthreads();
    float4 oacc = {0, 0, 0, 0};
    gemv4_acc<128>(w_out + h0 * 128, zs + row * SP, &oacc);
    float4 bo4 = *(const float4*)(b_out + h0);
    oacc.x += bo4.x; oacc.y += bo4.y; oacc.z += bo4.z; oacc.w += bo4.w;
    *(float4*)(out + t * HH + h0) = oacc;
}

extern "C" void kernel_launch(void* const* d_in, const int* in_sizes, int n_in,
                              void* d_out, int out_size, void* d_ws, size_t ws_size,
                              hipStream_t stream) {
    const float* emb   = (const float*)d_in[0];
    const int*   start = (const int*)  d_in[1];
    const float* w_in  = (const float*)d_in[2];
    const float* b_in  = (const float*)d_in[3];
    const float* w_out = (const float*)d_in[4];
    const float* b_out = (const float*)d_in[5];
    const float* w_f   = (const float*)d_in[6];
    const float* b_f   = (const float*)d_in[7];
    const float* w_i   = (const float*)d_in[8];
    const float* b_i   = (const float*)d_in[9];
    const float* w_v   = (const float*)d_in[10];
    const float* b_v   = (const float*)d_in[11];
    const float* w_q   = (const float*)d_in[12];
    const float* b_q   = (const float*)d_in[13];
    const float* w_k   = (const float*)d_in[14];
    const float* b_k   = (const float*)d_in[15];
    const float* w_o   = (const float*)d_in[16];
    const float* b_o   = (const float*)d_in[17];
    const float* w_ff  = (const float*)d_in[18];
    const float* b_ff  = (const float*)d_in[19];
    float* out = (float*)d_out;

    float* ws = (float*)d_ws;
    float* e   = ws; ws += TT * HH;
    float* k0b = ws; ws += TT * HH;
    float* v0b = ws; ws += TT * HH;
    float* q0b = ws; ws += TT * HH;
    float* o0b = ws; ws += TT * HH;
    float* k1b = ws; ws += TT * HH;
    float* v1b = ws; ws += TT * HH;
    float* q1b = ws; ws += TT * HH;
    float* o1b = ws; ws += TT * HH;
    float* g0  = ws; ws += TT;
    float* i0  = ws; ws += TT;
    float* g1  = ws; ws += TT;
    float* i1  = ws; ws += TT;

    dim3 grid(TT / ROWS), block(256);
    k1_kernel<<<grid, block, 0, stream>>>(
        emb, start, w_in, b_in,
        w_v, b_v, w_q, b_q, w_k, b_k, w_o, b_o, w_f, b_f, w_i, b_i,
        e, k0b, v0b, q0b, o0b, g0, i0);
    k2_kernel<<<grid, block, 0, stream>>>(
        start, e, k0b, v0b, q0b, o0b, g0, i0,
        w_ff, b_ff,
        w_v + HH * HH, b_v + HH, w_q + HH * HH, b_q + HH,
        w_k + HH * HH, b_k + HH, w_o + HH * HH, b_o + HH,
        w_f + HH, b_f + 1, w_i + HH, b_i + 1,
        k1b, v1b, q1b, o1b, g1, i1);
    k3_kernel<<<grid, block, 0, stream>>>(
        start, e, k1b, v1b, q1b, o1b, g1, i1,
        w_ff + HH * 2 * HH, b_ff + HH, w_out, b_out, out);
}